// Round 4
// baseline (404.953 us; speedup 1.0000x reference)
//
#include <hip/hip_runtime.h>
#include <cstdint>
#include <cstddef>

// ReservoirRNNCell: B=16, I=1024, H=2048
// out[b,o] = tanh( x[b,:]·Wih[o,:] + bih[o] + wsum/s ), where per (b,o):
//   s    = Σ_h E[o,h] * r(u[b,o,h])
//   wsum = Σ_h E[o,h] * r(u[b,o,h]) * hprev[b,h]
//   E[o,h] = exp((Whh[o,h]*mask[o,h])/tau),  r(u) = 1/log2(u)
// (Gumbel-softmax weights exp(l+g) = exp(l)*(-1/ln u); the constant -ln2
//  from using log2 cancels in the wsum/s ratio.)
//
// Block = 256 thr (4 waves) per output column o; E[o,:] staged once into LDS.
// Each wave streams 4 u-rows (b = wid, wid+4, wid+8, wid+12), 8 KB each,
// fully coalesced float4. __launch_bounds__(256,4) -> >=4 independent
// blocks/CU so staging/drain of one block overlaps streaming of others
// (the 1024-thr version was 1 lockstep block/CU with exposed stage+drain).

#define LOG2E 1.4426950408889634f

__global__ __launch_bounds__(256, 4) void rnn_fused_kernel(
    const float* __restrict__ x,      // [16,1024]
    const float* __restrict__ hprev,  // [16,2048]
    const float* __restrict__ Wih,    // [2048,1024]
    const float* __restrict__ bih,    // [2048]
    const float* __restrict__ Whh,    // [2048,2048]
    const float* __restrict__ temp,   // [1]
    const float* __restrict__ mask,   // [2048,2048]
    const float* __restrict__ u,      // [16,2048,2048]
    float* __restrict__ out)          // [16,2048]
{
  __shared__ float e_row[2048];

  const int o    = blockIdx.x;        // 0..2047
  const int tid  = threadIdx.x;       // 0..255
  const int lane = tid & 63;
  const int wid  = tid >> 6;          // 0..3

  // ---- stage E[o,:] into LDS (256 thr x 2 float4 = 2048 floats) ----
  {
    const float tau = fmaxf(temp[0], 1e-3f);
    const float sc  = LOG2E / tau;
    const float4* wp = (const float4*)(Whh  + ((size_t)o << 11));
    const float4* mp = (const float4*)(mask + ((size_t)o << 11));
#pragma unroll
    for (int i = 0; i < 2; ++i) {
      int idx = (i << 8) + tid;
      float4 w4 = wp[idx];
      float4 m4 = mp[idx];
      float4 e4;
      e4.x = __builtin_amdgcn_exp2f(w4.x * m4.x * sc);
      e4.y = __builtin_amdgcn_exp2f(w4.y * m4.y * sc);
      e4.z = __builtin_amdgcn_exp2f(w4.z * m4.z * sc);
      e4.w = __builtin_amdgcn_exp2f(w4.w * m4.w * sc);
      ((float4*)e_row)[idx] = e4;
    }
  }
  __syncthreads();

  const float4* ep4 = (const float4*)e_row;
  const float4* wip = (const float4*)(Wih + ((size_t)o << 10));
  const float   bo  = bih[o];

  // ---- each wave: 4 batch rows ----
#pragma unroll
  for (int r = 0; r < 4; ++r) {
    const int b = wid + (r << 2);     // 0..15
    const float4* up = (const float4*)(u + ((((size_t)b << 11) + o) << 11));
    const float4* hp = (const float4*)(hprev + ((size_t)b << 11));

    float s = 0.f, wsum = 0.f;
#pragma unroll
    for (int it = 0; it < 8; ++it) {
      int idx = (it << 6) + lane;     // 8*64*4 = 2048 floats per row
      float4 uu = up[idx];
      float4 hh = hp[idx];
      float4 ee = ep4[idx];           // contiguous ds_read_b128: conflict-free
      float w0 = ee.x * __builtin_amdgcn_rcpf(__builtin_amdgcn_logf(uu.x));
      float w1 = ee.y * __builtin_amdgcn_rcpf(__builtin_amdgcn_logf(uu.y));
      float w2 = ee.z * __builtin_amdgcn_rcpf(__builtin_amdgcn_logf(uu.z));
      float w3 = ee.w * __builtin_amdgcn_rcpf(__builtin_amdgcn_logf(uu.w));
      s += w0; wsum = fmaf(w0, hh.x, wsum);
      s += w1; wsum = fmaf(w1, hh.y, wsum);
      s += w2; wsum = fmaf(w2, hh.z, wsum);
      s += w3; wsum = fmaf(w3, hh.w, wsum);
    }

    // fused input_contrib: dot(x[b,:], Wih[o,:]) over I=1024 (L1-resident)
    const float4* xp = (const float4*)(x + ((size_t)b << 10));
    float ic = 0.f;
#pragma unroll
    for (int it = 0; it < 4; ++it) {
      int idx = (it << 6) + lane;
      float4 xx = xp[idx];
      float4 ww = wip[idx];
      ic = fmaf(xx.x, ww.x, ic);
      ic = fmaf(xx.y, ww.y, ic);
      ic = fmaf(xx.z, ww.z, ic);
      ic = fmaf(xx.w, ww.w, ic);
    }

    // wave-wide reduction (64 lanes)
#pragma unroll
    for (int off = 32; off > 0; off >>= 1) {
      s    += __shfl_xor(s,    off, 64);
      wsum += __shfl_xor(wsum, off, 64);
      ic   += __shfl_xor(ic,   off, 64);
    }

    if (lane == 0) {
      out[(b << 11) + o] = tanhf(ic + bo + wsum / s);
    }
  }
}

extern "C" void kernel_launch(void* const* d_in, const int* in_sizes, int n_in,
                              void* d_out, int out_size, void* d_ws, size_t ws_size,
                              hipStream_t stream) {
  const float* x     = (const float*)d_in[0];
  const float* hprev = (const float*)d_in[1];
  const float* Wih   = (const float*)d_in[2];
  const float* bih   = (const float*)d_in[3];
  const float* Whh   = (const float*)d_in[4];
  const float* temp  = (const float*)d_in[5];
  const float* mask  = (const float*)d_in[6];
  const float* u     = (const float*)d_in[7];
  float* out = (float*)d_out;

  rnn_fused_kernel<<<2048, 256, 0, stream>>>(x, hprev, Wih, bih, Whh, temp,
                                             mask, u, out);
}